// Round 14
// baseline (270.947 us; speedup 1.0000x reference)
//
#include <hip/hip_runtime.h>
#include <math.h>

#define N_NODES 30000
#define F_IN 256
#define E_RAW 300000
#define E_TOT (E_RAW + N_NODES)   /* 330000: edges + self loops */
#define HEADS 8
#define CH 128
#define HC 1024                   /* HEADS*CH */
#define OUTC 64
#define NEG_SLOPE 0.2f
#define CAP 64                    /* edges per LDS chunk in fused agg kernels */

typedef __attribute__((ext_vector_type(8))) short bf16x8;
typedef __attribute__((ext_vector_type(4))) float f32x4;
typedef __attribute__((ext_vector_type(2))) float f32x2;

/* ---------- helpers ---------- */
__device__ __forceinline__ float bf2f(unsigned short u) {
    return __uint_as_float(((unsigned)u) << 16);
}
__device__ __forceinline__ unsigned short f2bf(float f) {
    unsigned b = __float_as_uint(f);
    b += 0x7FFFu + ((b >> 16) & 1u);   /* round to nearest even */
    return (unsigned short)(b >> 16);
}
__device__ __forceinline__ void edge_sd(const int* __restrict__ ei, int e, int& s, int& d) {
    if (e < E_RAW) { s = ei[e]; d = ei[E_RAW + e]; }
    else           { s = e - E_RAW; d = s; }
}
/* async global->LDS, 16B per lane; LDS dest = wave-uniform base + lane*16 */
__device__ __forceinline__ void async_cp16(const void* g, void* l) {
    __builtin_amdgcn_global_load_lds((const __attribute__((address_space(1))) void*)g,
                                     (__attribute__((address_space(3))) void*)l, 16, 0, 0);
}
/* fp8 slot permutation: slot s -> original channel */
__device__ __forceinline__ int slotP(int s) {
    return ((s >> 6) << 6) + ((s >> 2) & 15) + ((s & 3) << 4);
}

/* ---------- fused prep: cvt_x | deg | cvt_w1t | cvt_w2t (independent jobs) ---------- */
#define NB_CVTX (N_NODES * F_IN / 4 / 256)      /* 7500 */
#define NB_DEG  ((E_TOT + 255) / 256)           /* 1290 */
#define NB_W1T  ((F_IN * HC + 255) / 256)       /* 1024 */
#define NB_W2T  ((HC * OUTC + 255) / 256)       /* 256 */
#define NB_PREP (NB_CVTX + NB_DEG + NB_W1T + NB_W2T)

__global__ __launch_bounds__(256)
void prep_kernel(const float* __restrict__ x, unsigned short* __restrict__ xb,
                 const float* __restrict__ W1, unsigned short* __restrict__ W1t,
                 const float* __restrict__ W2, unsigned short* __restrict__ W2t,
                 const int* __restrict__ ei, int* __restrict__ deg)
{
    const int b = blockIdx.x, t = threadIdx.x;
    if (b < NB_CVTX) {
        int i = b * 256 + t;
        const float4 v = reinterpret_cast<const float4*>(x)[i];
        ushort4 o;
        o.x = f2bf(v.x); o.y = f2bf(v.y); o.z = f2bf(v.z); o.w = f2bf(v.w);
        reinterpret_cast<ushort4*>(xb)[i] = o;
    } else if (b < NB_CVTX + NB_DEG) {
        int e = (b - NB_CVTX) * 256 + t;
        if (e < E_TOT) {
            int s, d; edge_sd(ei, e, s, d);
            atomicAdd(&deg[d], 1);
        }
    } else if (b < NB_CVTX + NB_DEG + NB_W1T) {
        int i = (b - NB_CVTX - NB_DEG) * 256 + t;
        if (i < F_IN * HC) {
            int k = i >> 10, n = i & (HC - 1);
            W1t[n * F_IN + k] = f2bf(W1[i]);
        }
    } else {
        /* W2t[n][s] = W2[P(s)][n] — k-axis carries the out1 slot permutation */
        int i = (b - NB_CVTX - NB_DEG - NB_W1T) * 256 + t;
        if (i < HC * OUTC) {
            int s = i >> 6, n = i & (OUTC - 1);
            W2t[n * HC + s] = f2bf(W2[slotP(s) * OUTC + n]);
        }
    }
}

/* ---------- layer-1 MFMA GEMM + fused attention dots, fp8 slot-layout C ----------
   A-persistent: 64-row blocks stage their A panel (64x256) ONCE (source-swizzled
   16B chunks, xor within 128B groups), then loop the 8 column tiles (= heads),
   staging only B chunks (128 cols x 64 k). 16 MFMA/wave per barrier. */
__global__ __launch_bounds__(256)
void gemm1_mfma(const unsigned short* __restrict__ A,
                const unsigned short* __restrict__ Bt,
                unsigned* __restrict__ Cp,      /* [M][256] dwords, fp8 slots */
                const float* __restrict__ att_src, const float* __restrict__ att_dst,
                float* __restrict__ a_src, float* __restrict__ a_dst, int M)
{
    __shared__ unsigned short Al[64 * 256];   /* 32 KB, persistent A panel */
    __shared__ unsigned short Bl[128 * 64];   /* 16 KB, per-(jt,k0) B chunk */
    __shared__ float s_src[64][2];
    __shared__ float s_dst[64][2];
    const int tid  = threadIdx.x;
    const int wave = tid >> 6, lane = tid & 63;
    const int quad = lane >> 4, l16 = lane & 15;
    const int wr = (wave >> 1) * 32;          /* wave rows: 0 or 32 */
    const int wc = (wave & 1) * 64;           /* wave cols within 128-tile */
    const int row0 = blockIdx.x * 64;

    /* stage A panel once: 64 rows x 32 chunks of 16B, swizzled at the source */
#pragma unroll
    for (int p = 0; p < 8; p++) {
        int idx = tid + 256 * p;
        int r = idx >> 5, q = idx & 31;
        int qs = (q & ~7) | ((q & 7) ^ (r & 7));
        async_cp16(A + (size_t)(row0 + r) * F_IN + qs * 8,
                   Al + (size_t)idx * 8);
    }

    for (int jt = 0; jt < 8; jt++) {          /* column tile = head */
        const int col0 = jt * 128;
        f32x4 acc[2][4];
#pragma unroll
        for (int i = 0; i < 2; i++)
#pragma unroll
            for (int j = 0; j < 4; j++) acc[i][j] = (f32x4){0.f, 0.f, 0.f, 0.f};

        for (int k0 = 0; k0 < 4; k0++) {      /* 64-k chunks */
#pragma unroll
            for (int p = 0; p < 4; p++) {     /* B: 128 rows x 8 chunks, swizzled */
                int idx = tid + 256 * p;
                int r = idx >> 3, q = idx & 7;
                async_cp16(Bt + (size_t)(col0 + r) * F_IN + (k0 * 8 + (q ^ (r & 7))) * 8,
                           Bl + (size_t)idx * 8);
            }
            __syncthreads();
#pragma unroll
            for (int kh = 0; kh < 2; kh++) {
                bf16x8 af[2], bg[4];
                const int cA = k0 * 8 + kh * 4 + quad;   /* full-row chunk idx */
#pragma unroll
                for (int i = 0; i < 2; i++) {
                    int rr = wr + i * 16 + l16;
                    int slot = (cA & ~7) | ((cA & 7) ^ (rr & 7));
                    af[i] = *reinterpret_cast<const bf16x8*>(Al + (rr * 32 + slot) * 8);
                }
                const int cB = kh * 4 + quad;
#pragma unroll
                for (int j = 0; j < 4; j++) {
                    int rr = wc + j * 16 + l16;
                    int slot = cB ^ (rr & 7);
                    bg[j] = *reinterpret_cast<const bf16x8*>(Bl + (rr * 8 + slot) * 8);
                }
#pragma unroll
                for (int i = 0; i < 2; i++)
#pragma unroll
                    for (int j = 0; j < 4; j++)
                        acc[i][j] = __builtin_amdgcn_mfma_f32_16x16x32_bf16(af[i], bg[j], acc[i][j], 0, 0, 0);
            }
            __syncthreads();
        }
        /* C write: pack 4 cols (stride 16) into one fp8 dword at slot-dword D */
        const int D = ((col0 + wc) >> 6) * 16 + l16;
#pragma unroll
        for (int i = 0; i < 2; i++) {
#pragma unroll
            for (int r = 0; r < 4; r++) {
                int row = row0 + wr + i * 16 + quad * 4 + r;
                if (row >= M) continue;
                int w8 = __builtin_amdgcn_cvt_pk_fp8_f32(acc[i][0][r], acc[i][1][r], 0, false);
                w8 = __builtin_amdgcn_cvt_pk_fp8_f32(acc[i][2][r], acc[i][3][r], w8, true);
                Cp[(size_t)row * 256 + D] = (unsigned)w8;
            }
        }
        /* fused attention dots for head = jt */
        {
            const float* asv = att_src + jt * CH;
            const float* adv = att_dst + jt * CH;
            float av[4], dv[4];
#pragma unroll
            for (int j = 0; j < 4; j++) {
                av[j] = asv[wc + j * 16 + l16];
                dv[j] = adv[wc + j * 16 + l16];
            }
#pragma unroll
            for (int i = 0; i < 2; i++) {
#pragma unroll
                for (int r = 0; r < 4; r++) {
                    float ps = 0.f, pd = 0.f;
#pragma unroll
                    for (int j = 0; j < 4; j++) {
                        float cc = acc[i][j][r];
                        ps += cc * av[j];
                        pd += cc * dv[j];
                    }
#pragma unroll
                    for (int o = 1; o < 16; o <<= 1) {
                        ps += __shfl_xor(ps, o);
                        pd += __shfl_xor(pd, o);
                    }
                    if (l16 == 0) {
                        int lr = wr + i * 16 + quad * 4 + r;
                        s_src[lr][wc >> 6] = ps;
                        s_dst[lr][wc >> 6] = pd;
                    }
                }
            }
            __syncthreads();
            if (tid < 64) {
                int row = row0 + tid;
                if (row < M) {
                    a_src[row * 8 + jt] = s_src[tid][0] + s_src[tid][1];
                    a_dst[row * 8 + jt] = s_dst[tid][0] + s_dst[tid][1];
                }
            }
            __syncthreads();
        }
    }
}

/* ---------- layer-2 MFMA GEMM + fused att2 dots ----------
   64-row tiles (469 blocks), BK=64 swizzled; wave w owns rows w*16..w*16+15. */
__global__ __launch_bounds__(256)
void gemm2_mfma(const unsigned short* __restrict__ A,
                const unsigned short* __restrict__ Bt,
                unsigned short* __restrict__ C,
                const float* __restrict__ att_src2, const float* __restrict__ att_dst2,
                float* __restrict__ a_src2, float* __restrict__ a_dst2, int M)
{
    __shared__ unsigned short Al[64 * 64];
    __shared__ unsigned short Bl[64 * 64];
    const int tid  = threadIdx.x;
    const int wave = tid >> 6, lane = tid & 63;
    const int quad = lane >> 4, l16 = lane & 15;
    const int wr = wave * 16;
    const int row0 = blockIdx.x * 64;

    f32x4 acc[4];
#pragma unroll
    for (int j = 0; j < 4; j++) acc[j] = (f32x4){0.f, 0.f, 0.f, 0.f};

    for (int k0 = 0; k0 < HC; k0 += 64) {
#pragma unroll
        for (int p = 0; p < 2; p++) {           /* A: 64 rows x 64 bf16, swizzled */
            int idx = tid + 256 * p;
            int r = idx >> 3, q = idx & 7;
            async_cp16(A + (size_t)(row0 + r) * HC + k0 + ((q ^ (r & 7)) * 8),
                       Al + (size_t)(wave * 64 + 256 * p) * 8);
        }
#pragma unroll
        for (int p = 0; p < 2; p++) {           /* B^T: 64 rows x 64 bf16, swizzled */
            int idx = tid + 256 * p;
            int r = idx >> 3, q = idx & 7;
            async_cp16(Bt + (size_t)r * HC + k0 + ((q ^ (r & 7)) * 8),
                       Bl + (size_t)(wave * 64 + 256 * p) * 8);
        }
        __syncthreads();
#pragma unroll
        for (int kh = 0; kh < 2; kh++) {
            const int cx = (kh * 4 + quad) ^ (l16 & 7);
            bf16x8 af, bg[4];
            af = *reinterpret_cast<const bf16x8*>(Al + ((wr + l16) * 8 + cx) * 8);
#pragma unroll
            for (int j = 0; j < 4; j++)
                bg[j] = *reinterpret_cast<const bf16x8*>(Bl + ((j * 16 + l16) * 8 + cx) * 8);
#pragma unroll
            for (int j = 0; j < 4; j++)
                acc[j] = __builtin_amdgcn_mfma_f32_16x16x32_bf16(af, bg[j], acc[j], 0, 0, 0);
        }
        __syncthreads();
    }
    float av[4], dv[4];
#pragma unroll
    for (int j = 0; j < 4; j++) {
        av[j] = att_src2[j * 16 + l16];
        dv[j] = att_dst2[j * 16 + l16];
    }
#pragma unroll
    for (int r = 0; r < 4; r++) {
        int row = row0 + wr + quad * 4 + r;
        float ps = 0.f, pd = 0.f;
#pragma unroll
        for (int j = 0; j < 4; j++) {
            float cc = acc[j][r];
            int col = j * 16 + l16;
            if (row < M) C[(size_t)row * OUTC + col] = f2bf(cc);
            ps += cc * av[j];
            pd += cc * dv[j];
        }
#pragma unroll
        for (int o = 1; o < 16; o <<= 1) {
            ps += __shfl_xor(ps, o);
            pd += __shfl_xor(pd, o);
        }
        if (l16 == 0 && row < M) {
            a_src2[row] = ps;
            a_dst2[row] = pd;
        }
    }
}

/* ---------- CSR build ---------- */
__global__ __launch_bounds__(256)
void alloc_kernel(const int* __restrict__ deg, int* __restrict__ rowstart,
                  int* __restrict__ cursor, int* __restrict__ counter)
{
    int d = blockIdx.x * 256 + threadIdx.x;
    int lane = threadIdx.x & 63;
    int v = (d < N_NODES) ? deg[d] : 0;
    int x = v;
#pragma unroll
    for (int o = 1; o < 64; o <<= 1) {
        int y = __shfl_up(x, o);
        if (lane >= o) x += y;
    }
    int excl = x - v;
    int total = __shfl(x, 63);
    int base = 0;
    if (lane == 63) base = atomicAdd(counter, total);
    base = __shfl(base, 63);
    if (d < N_NODES) {
        rowstart[d] = base + excl;
        cursor[d]   = base + excl;
    }
}

__global__ void scatter_kernel(const int* __restrict__ ei, int* __restrict__ cursor,
                               int* __restrict__ csr_src)
{
    int e = blockIdx.x * 256 + threadIdx.x;
    if (e >= E_TOT) return;
    int s, d; edge_sd(ei, e, s, d);
    int pos = atomicAdd(&cursor[d], 1);
    csr_src[pos] = s;
}

/* ---------- layer-1 fused softmax+aggregation, bias+ELU ----------
   fp8 h1 (slot layout): 4 nodes per 256-block, 64 threads/node,
   thread owns 16 fp8 channels (uint4 load) all within one head. */
__global__ __launch_bounds__(256)
void agg1_fused(const int* __restrict__ rowstart, const int* __restrict__ degv,
                const int* __restrict__ csr_src,
                const unsigned* __restrict__ h1p,     /* [N][256] fp8 dwords */
                const float* __restrict__ a_src1, const float* __restrict__ a_dst1,
                const float* __restrict__ b1, unsigned short* __restrict__ out1)
{
    const int t   = threadIdx.x;
    const int sub = t >> 6;            /* node within block: 0..3 */
    const int tl  = t & 63;            /* thread within node */
    const int h   = tl >> 3;           /* head (all 16 channels of tl in this head) */
    const int d   = blockIdx.x * 4 + sub;

    __shared__ float exps[4][CAP * 8];
    __shared__ int   srcs[4][CAP];
    __shared__ int   maxdeg_s;

    const int start = rowstart[d];
    const int deg   = degv[d];

    if (t == 0) maxdeg_s = 0;
    __syncthreads();
    if (tl == 0) atomicMax(&maxdeg_s, deg);
    __syncthreads();
    const int maxdeg = maxdeg_s;

    const float adst = a_dst1[d * 8 + h];
    const uint4* __restrict__ h1v = reinterpret_cast<const uint4*>(h1p);  /* row = 64 uint4 */

    float denom_part = 0.f;
    float acc[16];
#pragma unroll
    for (int k = 0; k < 16; k++) acc[k] = 0.f;

    for (int c0 = 0; c0 < maxdeg; c0 += CAP) {
        const int cend = min(deg - c0, CAP);
        /* phase 1: exps for my head; 8 lanes per head stride the chunk */
        for (int c = (tl & 7); c < cend; c += 8) {
            int s = csr_src[start + c0 + c];
            if (h == 0) srcs[sub][c] = s;
            float a = a_src1[s * 8 + h] + adst;
            float v = a > 0.f ? a : NEG_SLOPE * a;
            float ex = __expf(v);
            exps[sub][c * 8 + h] = ex;
            denom_part += ex;
        }
        __syncthreads();
        /* phase 2: 1-ahead pipelined fp8 gather */
        if (cend > 0) {
            int   s_cur = srcs[sub][0];
            float w_cur = exps[sub][h];
            uint4 u_cur = h1v[(size_t)s_cur * 64 + tl];
            for (int c = 0; c < cend; c++) {
                int   s_nxt = 0; float w_nxt = 0.f; uint4 u_nxt;
                if (c + 1 < cend) {
                    s_nxt = srcs[sub][c + 1];
                    w_nxt = exps[sub][(c + 1) * 8 + h];
                    u_nxt = h1v[(size_t)s_nxt * 64 + tl];
                }
#pragma unroll
                for (int dw = 0; dw < 4; dw++) {
                    unsigned wd = (&u_cur.x)[dw];
                    f32x2 lo = __builtin_amdgcn_cvt_pk_f32_fp8((int)wd, false);
                    f32x2 hi = __builtin_amdgcn_cvt_pk_f32_fp8((int)wd, true);
                    acc[dw * 4 + 0] += w_cur * lo.x;
                    acc[dw * 4 + 1] += w_cur * lo.y;
                    acc[dw * 4 + 2] += w_cur * hi.x;
                    acc[dw * 4 + 3] += w_cur * hi.y;
                }
                s_cur = s_nxt; w_cur = w_nxt; u_cur = u_nxt;
            }
        }
        __syncthreads();
    }
    /* denominator: reduce over the 8 lanes of this head */
#pragma unroll
    for (int o = 1; o < 8; o <<= 1) denom_part += __shfl_xor(denom_part, o);
    const float dinv = 1.f / (denom_part + 1e-16f);

    /* bias (gathered at original channels) + ELU, write bf16 slots 16tl..16tl+15 */
    unsigned short ov[16];
#pragma unroll
    for (int e = 0; e < 16; e++) {
        float v = acc[e] * dinv + b1[slotP(16 * tl + e)];
        v = v > 0.f ? v : __expf(v) - 1.f;
        ov[e] = f2bf(v);
    }
    uint4* op = reinterpret_cast<uint4*>(out1 + (size_t)d * HC + 16 * tl);
    op[0] = *reinterpret_cast<uint4*>(&ov[0]);
    op[1] = *reinterpret_cast<uint4*>(&ov[8]);
}

/* ---------- layer-2 fused softmax+agg + bias + log_softmax ----------
   4 nodes per 256-block; 4 edges in flight (16-lane groups); bf16 h2,
   each lane owns 4 channels (uint2 = 8B loads). */
__global__ __launch_bounds__(256)
void agg2_lsm(const int* __restrict__ rowstart, const int* __restrict__ degv,
              const int* __restrict__ csr_src,
              const unsigned short* __restrict__ h2,
              const float* __restrict__ a_src2, const float* __restrict__ a_dst2,
              const float* __restrict__ b2, float* __restrict__ out)
{
    const int t = threadIdx.x;
    const int sub  = t >> 6;
    const int lane = t & 63;
    const int eo   = lane >> 4;        /* edge offset 0..3 */
    const int cq   = lane & 15;        /* channel quad: channels 4cq..4cq+3 */
    const int d = blockIdx.x * 4 + sub;

    __shared__ float exs[4][CAP];
    __shared__ int   ss[4][CAP];
    __shared__ int   maxdeg_s;

    const int start = rowstart[d];
    const int deg   = degv[d];

    if (t == 0) maxdeg_s = 0;
    __syncthreads();
    if (lane == 0) atomicMax(&maxdeg_s, deg);
    __syncthreads();
    const int maxdeg = maxdeg_s;

    const float adst = a_dst2[d];
    const uint2* __restrict__ h2v = reinterpret_cast<const uint2*>(h2);  /* row = 16 uint2 */
    float denom_part = 0.f;
    float ax = 0.f, ay = 0.f, az = 0.f, aw = 0.f;

    for (int c0 = 0; c0 < maxdeg; c0 += CAP) {
        const int cend = min(deg - c0, CAP);
        for (int c = lane; c < cend; c += 64) {
            int s = csr_src[start + c0 + c];
            ss[sub][c] = s;
            float a = a_src2[s] + adst;
            float v = a > 0.f ? a : NEG_SLOPE * a;
            float ex = __expf(v);
            exs[sub][c] = ex;
            denom_part += ex;
        }
        __syncthreads();
        if (cend > 0) {
            int   cc = eo;
            float w0 = (cc < cend) ? exs[sub][cc] : 0.f;
            int   s0 = (cc < cend) ? ss[sub][cc] : ss[sub][0];
            uint2 u0 = h2v[(size_t)s0 * 16 + cq];
            for (int c = 0; c + 4 < cend; c += 4) {
                int cc1 = c + 4 + eo;
                float w1 = (cc1 < cend) ? exs[sub][cc1] : 0.f;
                int   s1 = (cc1 < cend) ? ss[sub][cc1] : ss[sub][0];
                uint2 u1 = h2v[(size_t)s1 * 16 + cq];
                ax += w0 * __uint_as_float(u0.x << 16);
                ay += w0 * __uint_as_float(u0.x & 0xFFFF0000u);
                az += w0 * __uint_as_float(u0.y << 16);
                aw += w0 * __uint_as_float(u0.y & 0xFFFF0000u);
                w0 = w1; s0 = s1; u0 = u1;
            }
            ax += w0 * __uint_as_float(u0.x << 16);
            ay += w0 * __uint_as_float(u0.x & 0xFFFF0000u);
            az += w0 * __uint_as_float(u0.y << 16);
            aw += w0 * __uint_as_float(u0.y & 0xFFFF0000u);
        }
        __syncthreads();
    }
    /* combine the 4 edge groups: lanes l, l^16, l^32, l^48 share a channel quad */
    ax += __shfl_xor(ax, 16); ax += __shfl_xor(ax, 32);
    ay += __shfl_xor(ay, 16); ay += __shfl_xor(ay, 32);
    az += __shfl_xor(az, 16); az += __shfl_xor(az, 32);
    aw += __shfl_xor(aw, 16); aw += __shfl_xor(aw, 32);
#pragma unroll
    for (int o = 32; o > 0; o >>= 1) denom_part += __shfl_xor(denom_part, o);
    const float dinv = 1.f / (denom_part + 1e-16f);

    float4 bb = reinterpret_cast<const float4*>(b2)[cq];
    float v0 = ax * dinv + bb.x;
    float v1 = ay * dinv + bb.y;
    float v2 = az * dinv + bb.z;
    float v3 = aw * dinv + bb.w;
    float m = fmaxf(fmaxf(v0, v1), fmaxf(v2, v3));
#pragma unroll
    for (int o = 1; o < 16; o <<= 1) m = fmaxf(m, __shfl_xor(m, o));
    float ex = __expf(v0 - m) + __expf(v1 - m) + __expf(v2 - m) + __expf(v3 - m);
    float ssum = ex;
#pragma unroll
    for (int o = 1; o < 16; o <<= 1) ssum += __shfl_xor(ssum, o);
    if (eo == 0) {
        float lg = __logf(ssum);
        reinterpret_cast<float4*>(out + (size_t)d * OUTC)[cq] =
            make_float4(v0 - m - lg, v1 - m - lg, v2 - m - lg, v3 - m - lg);
    }
}

extern "C" void kernel_launch(void* const* d_in, const int* in_sizes, int n_in,
                              void* d_out, int out_size, void* d_ws, size_t ws_size,
                              hipStream_t stream)
{
    const float* x   = (const float*)d_in[0];
    const int*   ei  = (const int*)d_in[1];
    const float* W1  = (const float*)d_in[2];
    const float* as1 = (const float*)d_in[3];
    const float* ad1 = (const float*)d_in[4];
    const float* b1  = (const float*)d_in[5];
    const float* W2  = (const float*)d_in[6];
    const float* as2 = (const float*)d_in[7];
    const float* ad2 = (const float*)d_in[8];
    const float* b2  = (const float*)d_in[9];

    char* p = (char*)d_ws;
    auto alloc = [&](size_t bytes) { char* r = p; p += (bytes + 255) & ~(size_t)255; return r; };

    /* region 0: h1p (fp8, 30.72 MB; sized 61.44) — dead after agg1; layer-2 aliases it */
    char* region0 = (char*)alloc((size_t)N_NODES * HC * 2);
    unsigned* h1p = (unsigned*)region0;

    /* region 1: out1 (bf16 slot-layout, 61.44 MB); xb/W1t (dead after gemm1) alias it */
    char* region1 = (char*)alloc((size_t)N_NODES * HC * 2);
    unsigned short* out1 = (unsigned short*)region1;
    unsigned short* xb   = (unsigned short*)region1;
    unsigned short* W1t  = (unsigned short*)(region1 + (size_t)N_NODES * F_IN * 2 + 256);

    unsigned short* W2t = (unsigned short*)alloc((size_t)OUTC * HC * 2);

    float* a_src1   = (float*)alloc((size_t)N_NODES * HEADS * 4);
    float* a_dst1   = (float*)alloc((size_t)N_NODES * HEADS * 4);
    int*   deg      = (int*)alloc((size_t)(N_NODES + 1) * 4);  /* +1: alloc counter */
    int*   counter  = deg + N_NODES;
    int*   rowstart = (int*)alloc((size_t)N_NODES * 4);
    int*   cursor   = (int*)alloc((size_t)N_NODES * 4);
    int*   csr_src  = (int*)alloc((size_t)E_TOT * 4);

    /* layer-2 buffers aliased into region0 */
    char* q = region0;
    auto alias = [&](size_t bytes) { char* r = q; q += (bytes + 255) & ~(size_t)255; return r; };
    unsigned short* h2 = (unsigned short*)alias((size_t)N_NODES * OUTC * 2);
    float* a_src2  = (float*)alias((size_t)N_NODES * 4);
    float* a_dst2  = (float*)alias((size_t)N_NODES * 4);

    hipMemsetAsync(deg, 0, (size_t)(N_NODES + 1) * 4, stream);

    /* fused prep: cvt_x | deg | cvt_w1t | cvt_w2t */
    prep_kernel<<<NB_PREP, 256, 0, stream>>>(x, xb, W1, W1t, W2, W2t, ei, deg);

    /* CSR build (parallel, unordered ranges) */
    alloc_kernel<<<(N_NODES + 255) / 256, 256, 0, stream>>>(deg, rowstart, cursor, counter);
    scatter_kernel<<<(E_TOT + 255) / 256, 256, 0, stream>>>(ei, cursor, csr_src);

    /* layer 1 (A-persistent gemm1; att dots fused; h1 stored fp8 slot-layout) */
    gemm1_mfma<<<(N_NODES + 63) / 64, 256, 0, stream>>>(
        xb, W1t, h1p, as1, ad1, a_src1, a_dst1, N_NODES);
    agg1_fused<<<N_NODES / 4, 256, 0, stream>>>(rowstart, deg, csr_src, h1p, a_src1, a_dst1, b1, out1);

    /* layer 2 (h1p dead; aliased buffers safe, stream-ordered; att2 fused into gemm2) */
    gemm2_mfma<<<(N_NODES + 63) / 64, 256, 0, stream>>>(
        out1, W2t, h2, as2, ad2, a_src2, a_dst2, N_NODES);
    agg2_lsm<<<N_NODES / 4, 256, 0, stream>>>(rowstart, deg, csr_src, h2, a_src2, a_dst2, b2, (float*)d_out);
}

// Round 15
// 258.717 us; speedup vs baseline: 1.0473x; 1.0473x over previous
//
#include <hip/hip_runtime.h>
#include <math.h>

#define N_NODES 30000
#define F_IN 256
#define E_RAW 300000
#define E_TOT (E_RAW + N_NODES)   /* 330000: edges + self loops */
#define HEADS 8
#define CH 128
#define HC 1024                   /* HEADS*CH */
#define OUTC 64
#define NEG_SLOPE 0.2f
#define CAP 64                    /* edges per LDS chunk in fused agg kernels */

typedef __attribute__((ext_vector_type(8))) short bf16x8;
typedef __attribute__((ext_vector_type(4))) float f32x4;
typedef __attribute__((ext_vector_type(2))) float f32x2;

/* ---------- helpers ---------- */
__device__ __forceinline__ float bf2f(unsigned short u) {
    return __uint_as_float(((unsigned)u) << 16);
}
__device__ __forceinline__ unsigned short f2bf(float f) {
    unsigned b = __float_as_uint(f);
    b += 0x7FFFu + ((b >> 16) & 1u);   /* round to nearest even */
    return (unsigned short)(b >> 16);
}
__device__ __forceinline__ void edge_sd(const int* __restrict__ ei, int e, int& s, int& d) {
    if (e < E_RAW) { s = ei[e]; d = ei[E_RAW + e]; }
    else           { s = e - E_RAW; d = s; }
}
/* async global->LDS, 16B per lane; LDS dest = wave-uniform base + lane*16 */
__device__ __forceinline__ void async_cp16(const void* g, void* l) {
    __builtin_amdgcn_global_load_lds((const __attribute__((address_space(1))) void*)g,
                                     (__attribute__((address_space(3))) void*)l, 16, 0, 0);
}
/* fp8 slot permutation: slot s -> original channel */
__device__ __forceinline__ int slotP(int s) {
    return ((s >> 6) << 6) + ((s >> 2) & 15) + ((s & 3) << 4);
}
/* wave-local LDS handoff: DS ops from one wave complete in order; we only
   need to stop compiler reordering across the phase boundary. */
__device__ __forceinline__ void wave_sync() {
    __builtin_amdgcn_fence(__ATOMIC_ACQ_REL, "wavefront");
    __builtin_amdgcn_wave_barrier();
}

/* ---------- fused prep: cvt_x | deg | cvt_w1t | cvt_w2t (independent jobs) ---------- */
#define NB_CVTX (N_NODES * F_IN / 4 / 256)      /* 7500 */
#define NB_DEG  ((E_TOT + 255) / 256)           /* 1290 */
#define NB_W1T  ((F_IN * HC + 255) / 256)       /* 1024 */
#define NB_W2T  ((HC * OUTC + 255) / 256)       /* 256 */
#define NB_PREP (NB_CVTX + NB_DEG + NB_W1T + NB_W2T)

__global__ __launch_bounds__(256)
void prep_kernel(const float* __restrict__ x, unsigned short* __restrict__ xb,
                 const float* __restrict__ W1, unsigned short* __restrict__ W1t,
                 const float* __restrict__ W2, unsigned short* __restrict__ W2t,
                 const int* __restrict__ ei, int* __restrict__ deg)
{
    const int b = blockIdx.x, t = threadIdx.x;
    if (b < NB_CVTX) {
        int i = b * 256 + t;
        const float4 v = reinterpret_cast<const float4*>(x)[i];
        ushort4 o;
        o.x = f2bf(v.x); o.y = f2bf(v.y); o.z = f2bf(v.z); o.w = f2bf(v.w);
        reinterpret_cast<ushort4*>(xb)[i] = o;
    } else if (b < NB_CVTX + NB_DEG) {
        int e = (b - NB_CVTX) * 256 + t;
        if (e < E_TOT) {
            int s, d; edge_sd(ei, e, s, d);
            atomicAdd(&deg[d], 1);
        }
    } else if (b < NB_CVTX + NB_DEG + NB_W1T) {
        int i = (b - NB_CVTX - NB_DEG) * 256 + t;
        if (i < F_IN * HC) {
            int k = i >> 10, n = i & (HC - 1);
            W1t[n * F_IN + k] = f2bf(W1[i]);
        }
    } else {
        /* W2t[n][s] = W2[P(s)][n] — k-axis carries the out1 slot permutation */
        int i = (b - NB_CVTX - NB_DEG - NB_W1T) * 256 + t;
        if (i < HC * OUTC) {
            int s = i >> 6, n = i & (OUTC - 1);
            W2t[n * HC + s] = f2bf(W2[slotP(s) * OUTC + n]);
        }
    }
}

/* ---------- layer-1 MFMA GEMM + fused attention dots, fp8 slot-layout C ----------
   R13 form (128x128 tile, BK=64, XOR-swizzled LDS). A-persistent variant (R14)
   regressed: L2 already deduplicated the A re-reads; it added B traffic+barriers. */
__global__ __launch_bounds__(256)
void gemm1_mfma(const unsigned short* __restrict__ A,
                const unsigned short* __restrict__ Bt,
                unsigned* __restrict__ Cp,      /* [M][256] dwords, fp8 slots */
                const float* __restrict__ att_src, const float* __restrict__ att_dst,
                float* __restrict__ a_src, float* __restrict__ a_dst, int M)
{
    __shared__ unsigned short Al[128 * 64];
    __shared__ unsigned short Bl[128 * 64];
    __shared__ float s_src[128][2];
    __shared__ float s_dst[128][2];
    const int tid  = threadIdx.x;
    const int wave = tid >> 6, lane = tid & 63;
    const int quad = lane >> 4, l16 = lane & 15;
    const int wr = (wave >> 1) * 64, wc = (wave & 1) * 64;
    const int row0 = blockIdx.y * 128;
    const int col0 = blockIdx.x * 128;

    f32x4 acc[4][4];
#pragma unroll
    for (int i = 0; i < 4; i++)
#pragma unroll
        for (int j = 0; j < 4; j++) acc[i][j] = (f32x4){0.f, 0.f, 0.f, 0.f};

    for (int k0 = 0; k0 < F_IN; k0 += 64) {
#pragma unroll
        for (int p = 0; p < 4; p++) {           /* A: 128 rows x 64 bf16, swizzled */
            int idx = tid + 256 * p;
            int r = idx >> 3, q = idx & 7;
            async_cp16(A + (size_t)(row0 + r) * F_IN + k0 + ((q ^ (r & 7)) * 8),
                       Al + (size_t)(wave * 64 + 256 * p) * 8);
        }
#pragma unroll
        for (int p = 0; p < 4; p++) {           /* B^T: 128 rows x 64 bf16, swizzled */
            int idx = tid + 256 * p;
            int r = idx >> 3, q = idx & 7;
            async_cp16(Bt + (size_t)(col0 + r) * F_IN + k0 + ((q ^ (r & 7)) * 8),
                       Bl + (size_t)(wave * 64 + 256 * p) * 8);
        }
        __syncthreads();
#pragma unroll
        for (int kh = 0; kh < 2; kh++) {        /* two k-halves, sequential (reg-lean) */
            const int cx = (kh * 4 + quad) ^ (l16 & 7);
            bf16x8 af[4], bg[4];
#pragma unroll
            for (int i = 0; i < 4; i++)
                af[i] = *reinterpret_cast<const bf16x8*>(Al + ((wr + i * 16 + l16) * 8 + cx) * 8);
#pragma unroll
            for (int j = 0; j < 4; j++)
                bg[j] = *reinterpret_cast<const bf16x8*>(Bl + ((wc + j * 16 + l16) * 8 + cx) * 8);
#pragma unroll
            for (int i = 0; i < 4; i++)
#pragma unroll
                for (int j = 0; j < 4; j++)
                    acc[i][j] = __builtin_amdgcn_mfma_f32_16x16x32_bf16(af[i], bg[j], acc[i][j], 0, 0, 0);
        }
        __syncthreads();
    }
    /* C write: pack 4 cols (j=0..3, stride 16) into one fp8 dword at slot-dword D */
    const int D = ((col0 + wc) >> 6) * 16 + l16;
#pragma unroll
    for (int i = 0; i < 4; i++) {
#pragma unroll
        for (int r = 0; r < 4; r++) {
            int row = row0 + wr + i * 16 + quad * 4 + r;
            if (row >= M) continue;
            int w8 = __builtin_amdgcn_cvt_pk_fp8_f32(acc[i][0][r], acc[i][1][r], 0, false);
            w8 = __builtin_amdgcn_cvt_pk_fp8_f32(acc[i][2][r], acc[i][3][r], w8, true);
            Cp[(size_t)row * 256 + D] = (unsigned)w8;
        }
    }
    /* fused attention dots for head = blockIdx.x */
    const float* asv = att_src + blockIdx.x * CH;
    const float* adv = att_dst + blockIdx.x * CH;
    float av[4], dv[4];
#pragma unroll
    for (int j = 0; j < 4; j++) {
        av[j] = asv[wc + j * 16 + l16];
        dv[j] = adv[wc + j * 16 + l16];
    }
#pragma unroll
    for (int i = 0; i < 4; i++) {
#pragma unroll
        for (int r = 0; r < 4; r++) {
            float ps = 0.f, pd = 0.f;
#pragma unroll
            for (int j = 0; j < 4; j++) {
                float cc = acc[i][j][r];
                ps += cc * av[j];
                pd += cc * dv[j];
            }
#pragma unroll
            for (int o = 1; o < 16; o <<= 1) {
                ps += __shfl_xor(ps, o);
                pd += __shfl_xor(pd, o);
            }
            if (l16 == 0) {
                int lr = wr + i * 16 + quad * 4 + r;
                s_src[lr][wc >> 6] = ps;
                s_dst[lr][wc >> 6] = pd;
            }
        }
    }
    __syncthreads();
    if (tid < 128) {
        int row = row0 + tid;
        if (row < M) {
            a_src[row * 8 + blockIdx.x] = s_src[tid][0] + s_src[tid][1];
            a_dst[row * 8 + blockIdx.x] = s_dst[tid][0] + s_dst[tid][1];
        }
    }
}

/* ---------- layer-2 MFMA GEMM + fused att2 dots ----------
   64-row tiles (469 blocks), BK=64 swizzled; wave w owns rows w*16..w*16+15. */
__global__ __launch_bounds__(256)
void gemm2_mfma(const unsigned short* __restrict__ A,
                const unsigned short* __restrict__ Bt,
                unsigned short* __restrict__ C,
                const float* __restrict__ att_src2, const float* __restrict__ att_dst2,
                float* __restrict__ a_src2, float* __restrict__ a_dst2, int M)
{
    __shared__ unsigned short Al[64 * 64];
    __shared__ unsigned short Bl[64 * 64];
    const int tid  = threadIdx.x;
    const int wave = tid >> 6, lane = tid & 63;
    const int quad = lane >> 4, l16 = lane & 15;
    const int wr = wave * 16;
    const int row0 = blockIdx.x * 64;

    f32x4 acc[4];
#pragma unroll
    for (int j = 0; j < 4; j++) acc[j] = (f32x4){0.f, 0.f, 0.f, 0.f};

    for (int k0 = 0; k0 < HC; k0 += 64) {
#pragma unroll
        for (int p = 0; p < 2; p++) {           /* A: 64 rows x 64 bf16, swizzled */
            int idx = tid + 256 * p;
            int r = idx >> 3, q = idx & 7;
            async_cp16(A + (size_t)(row0 + r) * HC + k0 + ((q ^ (r & 7)) * 8),
                       Al + (size_t)(wave * 64 + 256 * p) * 8);
        }
#pragma unroll
        for (int p = 0; p < 2; p++) {           /* B^T: 64 rows x 64 bf16, swizzled */
            int idx = tid + 256 * p;
            int r = idx >> 3, q = idx & 7;
            async_cp16(Bt + (size_t)r * HC + k0 + ((q ^ (r & 7)) * 8),
                       Bl + (size_t)(wave * 64 + 256 * p) * 8);
        }
        __syncthreads();
#pragma unroll
        for (int kh = 0; kh < 2; kh++) {
            const int cx = (kh * 4 + quad) ^ (l16 & 7);
            bf16x8 af, bg[4];
            af = *reinterpret_cast<const bf16x8*>(Al + ((wr + l16) * 8 + cx) * 8);
#pragma unroll
            for (int j = 0; j < 4; j++)
                bg[j] = *reinterpret_cast<const bf16x8*>(Bl + ((j * 16 + l16) * 8 + cx) * 8);
#pragma unroll
            for (int j = 0; j < 4; j++)
                acc[j] = __builtin_amdgcn_mfma_f32_16x16x32_bf16(af, bg[j], acc[j], 0, 0, 0);
        }
        __syncthreads();
    }
    float av[4], dv[4];
#pragma unroll
    for (int j = 0; j < 4; j++) {
        av[j] = att_src2[j * 16 + l16];
        dv[j] = att_dst2[j * 16 + l16];
    }
#pragma unroll
    for (int r = 0; r < 4; r++) {
        int row = row0 + wr + quad * 4 + r;
        float ps = 0.f, pd = 0.f;
#pragma unroll
        for (int j = 0; j < 4; j++) {
            float cc = acc[j][r];
            int col = j * 16 + l16;
            if (row < M) C[(size_t)row * OUTC + col] = f2bf(cc);
            ps += cc * av[j];
            pd += cc * dv[j];
        }
#pragma unroll
        for (int o = 1; o < 16; o <<= 1) {
            ps += __shfl_xor(ps, o);
            pd += __shfl_xor(pd, o);
        }
        if (l16 == 0 && row < M) {
            a_src2[row] = ps;
            a_dst2[row] = pd;
        }
    }
}

/* ---------- CSR build ---------- */
__global__ __launch_bounds__(256)
void alloc_kernel(const int* __restrict__ deg, int* __restrict__ rowstart,
                  int* __restrict__ cursor, int* __restrict__ counter)
{
    int d = blockIdx.x * 256 + threadIdx.x;
    int lane = threadIdx.x & 63;
    int v = (d < N_NODES) ? deg[d] : 0;
    int x = v;
#pragma unroll
    for (int o = 1; o < 64; o <<= 1) {
        int y = __shfl_up(x, o);
        if (lane >= o) x += y;
    }
    int excl = x - v;
    int total = __shfl(x, 63);
    int base = 0;
    if (lane == 63) base = atomicAdd(counter, total);
    base = __shfl(base, 63);
    if (d < N_NODES) {
        rowstart[d] = base + excl;
        cursor[d]   = base + excl;
    }
}

__global__ void scatter_kernel(const int* __restrict__ ei, int* __restrict__ cursor,
                               int* __restrict__ csr_src)
{
    int e = blockIdx.x * 256 + threadIdx.x;
    if (e >= E_TOT) return;
    int s, d; edge_sd(ei, e, s, d);
    int pos = atomicAdd(&cursor[d], 1);
    csr_src[pos] = s;
}

/* ---------- layer-1 fused softmax+aggregation, bias+ELU ----------
   fp8 h1 (slot layout): 4 nodes per 256-block, each node = ONE WAVE
   (wave-local LDS handoff, no block barriers, no maxdeg coupling). */
__global__ __launch_bounds__(256)
void agg1_fused(const int* __restrict__ rowstart, const int* __restrict__ degv,
                const int* __restrict__ csr_src,
                const unsigned* __restrict__ h1p,     /* [N][256] fp8 dwords */
                const float* __restrict__ a_src1, const float* __restrict__ a_dst1,
                const float* __restrict__ b1, unsigned short* __restrict__ out1)
{
    const int t   = threadIdx.x;
    const int sub = t >> 6;            /* node within block: 0..3 (= wave) */
    const int tl  = t & 63;            /* lane within node */
    const int h   = tl >> 3;           /* head (all 16 channels of tl in this head) */
    const int d   = blockIdx.x * 4 + sub;

    __shared__ float exps[4][CAP * 8];
    __shared__ int   srcs[4][CAP];

    const int start = rowstart[d];
    const int deg   = degv[d];

    const float adst = a_dst1[d * 8 + h];
    const uint4* __restrict__ h1v = reinterpret_cast<const uint4*>(h1p);  /* row = 64 uint4 */

    float denom_part = 0.f;
    float acc[16];
#pragma unroll
    for (int k = 0; k < 16; k++) acc[k] = 0.f;

    for (int c0 = 0; c0 < deg; c0 += CAP) {
        const int cend = min(deg - c0, CAP);
        /* phase 1: exps for my head; 8 lanes per head stride the chunk */
        for (int c = (tl & 7); c < cend; c += 8) {
            int s = csr_src[start + c0 + c];
            if (h == 0) srcs[sub][c] = s;
            float a = a_src1[s * 8 + h] + adst;
            float v = a > 0.f ? a : NEG_SLOPE * a;
            float ex = __expf(v);
            exps[sub][c * 8 + h] = ex;
            denom_part += ex;
        }
        wave_sync();
        /* phase 2: 1-ahead pipelined fp8 gather */
        {
            int   s_cur = srcs[sub][0];
            float w_cur = exps[sub][h];
            uint4 u_cur = h1v[(size_t)s_cur * 64 + tl];
            for (int c = 0; c < cend; c++) {
                int   s_nxt = 0; float w_nxt = 0.f; uint4 u_nxt;
                if (c + 1 < cend) {
                    s_nxt = srcs[sub][c + 1];
                    w_nxt = exps[sub][(c + 1) * 8 + h];
                    u_nxt = h1v[(size_t)s_nxt * 64 + tl];
                }
#pragma unroll
                for (int dw = 0; dw < 4; dw++) {
                    unsigned wd = (&u_cur.x)[dw];
                    f32x2 lo = __builtin_amdgcn_cvt_pk_f32_fp8((int)wd, false);
                    f32x2 hi = __builtin_amdgcn_cvt_pk_f32_fp8((int)wd, true);
                    acc[dw * 4 + 0] += w_cur * lo.x;
                    acc[dw * 4 + 1] += w_cur * lo.y;
                    acc[dw * 4 + 2] += w_cur * hi.x;
                    acc[dw * 4 + 3] += w_cur * hi.y;
                }
                s_cur = s_nxt; w_cur = w_nxt; u_cur = u_nxt;
            }
        }
        wave_sync();
    }
    /* denominator: reduce over the 8 lanes of this head */
#pragma unroll
    for (int o = 1; o < 8; o <<= 1) denom_part += __shfl_xor(denom_part, o);
    const float dinv = 1.f / (denom_part + 1e-16f);

    /* bias (gathered at original channels) + ELU, write bf16 slots 16tl..16tl+15 */
    unsigned short ov[16];
#pragma unroll
    for (int e = 0; e < 16; e++) {
        float v = acc[e] * dinv + b1[slotP(16 * tl + e)];
        v = v > 0.f ? v : __expf(v) - 1.f;
        ov[e] = f2bf(v);
    }
    uint4* op = reinterpret_cast<uint4*>(out1 + (size_t)d * HC + 16 * tl);
    op[0] = *reinterpret_cast<uint4*>(&ov[0]);
    op[1] = *reinterpret_cast<uint4*>(&ov[8]);
}

/* ---------- layer-2 fused softmax+agg + bias + log_softmax ----------
   4 nodes per 256-block, each node = ONE WAVE (wave-local handoff);
   4 edges in flight (16-lane groups); bf16 h2, uint2 loads. */
__global__ __launch_bounds__(256)
void agg2_lsm(const int* __restrict__ rowstart, const int* __restrict__ degv,
              const int* __restrict__ csr_src,
              const unsigned short* __restrict__ h2,
              const float* __restrict__ a_src2, const float* __restrict__ a_dst2,
              const float* __restrict__ b2, float* __restrict__ out)
{
    const int t = threadIdx.x;
    const int sub  = t >> 6;
    const int lane = t & 63;
    const int eo   = lane >> 4;        /* edge offset 0..3 */
    const int cq   = lane & 15;        /* channel quad: channels 4cq..4cq+3 */
    const int d = blockIdx.x * 4 + sub;

    __shared__ float exs[4][CAP];
    __shared__ int   ss[4][CAP];

    const int start = rowstart[d];
    const int deg   = degv[d];

    const float adst = a_dst2[d];
    const uint2* __restrict__ h2v = reinterpret_cast<const uint2*>(h2);  /* row = 16 uint2 */
    float denom_part = 0.f;
    float ax = 0.f, ay = 0.f, az = 0.f, aw = 0.f;

    for (int c0 = 0; c0 < deg; c0 += CAP) {
        const int cend = min(deg - c0, CAP);
        for (int c = lane; c < cend; c += 64) {
            int s = csr_src[start + c0 + c];
            ss[sub][c] = s;
            float a = a_src2[s] + adst;
            float v = a > 0.f ? a : NEG_SLOPE * a;
            float ex = __expf(v);
            exs[sub][c] = ex;
            denom_part += ex;
        }
        wave_sync();
        {
            int   cc = eo;
            float w0 = (cc < cend) ? exs[sub][cc] : 0.f;
            int   s0 = (cc < cend) ? ss[sub][cc] : ss[sub][0];
            uint2 u0 = h2v[(size_t)s0 * 16 + cq];
            for (int c = 0; c + 4 < cend; c += 4) {
                int cc1 = c + 4 + eo;
                float w1 = (cc1 < cend) ? exs[sub][cc1] : 0.f;
                int   s1 = (cc1 < cend) ? ss[sub][cc1] : ss[sub][0];
                uint2 u1 = h2v[(size_t)s1 * 16 + cq];
                ax += w0 * __uint_as_float(u0.x << 16);
                ay += w0 * __uint_as_float(u0.x & 0xFFFF0000u);
                az += w0 * __uint_as_float(u0.y << 16);
                aw += w0 * __uint_as_float(u0.y & 0xFFFF0000u);
                w0 = w1; s0 = s1; u0 = u1;
            }
            ax += w0 * __uint_as_float(u0.x << 16);
            ay += w0 * __uint_as_float(u0.x & 0xFFFF0000u);
            az += w0 * __uint_as_float(u0.y << 16);
            aw += w0 * __uint_as_float(u0.y & 0xFFFF0000u);
        }
        wave_sync();
    }
    /* combine the 4 edge groups: lanes l, l^16, l^32, l^48 share a channel quad */
    ax += __shfl_xor(ax, 16); ax += __shfl_xor(ax, 32);
    ay += __shfl_xor(ay, 16); ay += __shfl_xor(ay, 32);
    az += __shfl_xor(az, 16); az += __shfl_xor(az, 32);
    aw += __shfl_xor(aw, 16); aw += __shfl_xor(aw, 32);
#pragma unroll
    for (int o = 32; o > 0; o >>= 1) denom_part += __shfl_xor(denom_part, o);
    const float dinv = 1.f / (denom_part + 1e-16f);

    float4 bb = reinterpret_cast<const float4*>(b2)[cq];
    float v0 = ax * dinv + bb.x;
    float v1 = ay * dinv + bb.y;
    float v2 = az * dinv + bb.z;
    float v3 = aw * dinv + bb.w;
    float m = fmaxf(fmaxf(v0, v1), fmaxf(v2, v3));
#pragma unroll
    for (int o = 1; o < 16; o <<= 1) m = fmaxf(m, __shfl_xor(m, o));
    float ex = __expf(v0 - m) + __expf(v1 - m) + __expf(v2 - m) + __expf(v3 - m);
    float ssum = ex;
#pragma unroll
    for (int o = 1; o < 16; o <<= 1) ssum += __shfl_xor(ssum, o);
    if (eo == 0) {
        float lg = __logf(ssum);
        reinterpret_cast<float4*>(out + (size_t)d * OUTC)[cq] =
            make_float4(v0 - m - lg, v1 - m - lg, v2 - m - lg, v3 - m - lg);
    }
}

extern "C" void kernel_launch(void* const* d_in, const int* in_sizes, int n_in,
                              void* d_out, int out_size, void* d_ws, size_t ws_size,
                              hipStream_t stream)
{
    const float* x   = (const float*)d_in[0];
    const int*   ei  = (const int*)d_in[1];
    const float* W1  = (const float*)d_in[2];
    const float* as1 = (const float*)d_in[3];
    const float* ad1 = (const float*)d_in[4];
    const float* b1  = (const float*)d_in[5];
    const float* W2  = (const float*)d_in[6];
    const float* as2 = (const float*)d_in[7];
    const float* ad2 = (const float*)d_in[8];
    const float* b2  = (const float*)d_in[9];

    char* p = (char*)d_ws;
    auto alloc = [&](size_t bytes) { char* r = p; p += (bytes + 255) & ~(size_t)255; return r; };

    /* region 0: h1p (fp8, 30.72 MB; sized 61.44) — dead after agg1; layer-2 aliases it */
    char* region0 = (char*)alloc((size_t)N_NODES * HC * 2);
    unsigned* h1p = (unsigned*)region0;

    /* region 1: out1 (bf16 slot-layout, 61.44 MB); xb/W1t (dead after gemm1) alias it */
    char* region1 = (char*)alloc((size_t)N_NODES * HC * 2);
    unsigned short* out1 = (unsigned short*)region1;
    unsigned short* xb   = (unsigned short*)region1;
    unsigned short* W1t  = (unsigned short*)(region1 + (size_t)N_NODES * F_IN * 2 + 256);

    unsigned short* W2t = (unsigned short*)alloc((size_t)OUTC * HC * 2);

    float* a_src1   = (float*)alloc((size_t)N_NODES * HEADS * 4);
    float* a_dst1   = (float*)alloc((size_t)N_NODES * HEADS * 4);
    int*   deg      = (int*)alloc((size_t)(N_NODES + 1) * 4);  /* +1: alloc counter */
    int*   counter  = deg + N_NODES;
    int*   rowstart = (int*)alloc((size_t)N_NODES * 4);
    int*   cursor   = (int*)alloc((size_t)N_NODES * 4);
    int*   csr_src  = (int*)alloc((size_t)E_TOT * 4);

    /* layer-2 buffers aliased into region0 */
    char* q = region0;
    auto alias = [&](size_t bytes) { char* r = q; q += (bytes + 255) & ~(size_t)255; return r; };
    unsigned short* h2 = (unsigned short*)alias((size_t)N_NODES * OUTC * 2);
    float* a_src2  = (float*)alias((size_t)N_NODES * 4);
    float* a_dst2  = (float*)alias((size_t)N_NODES * 4);

    hipMemsetAsync(deg, 0, (size_t)(N_NODES + 1) * 4, stream);

    /* fused prep: cvt_x | deg | cvt_w1t | cvt_w2t */
    prep_kernel<<<NB_PREP, 256, 0, stream>>>(x, xb, W1, W1t, W2, W2t, ei, deg);

    /* CSR build (parallel, unordered ranges) */
    alloc_kernel<<<(N_NODES + 255) / 256, 256, 0, stream>>>(deg, rowstart, cursor, counter);
    scatter_kernel<<<(E_TOT + 255) / 256, 256, 0, stream>>>(ei, cursor, csr_src);

    /* layer 1 (R13 gemm1; att dots fused; h1 stored fp8 slot-layout) */
    gemm1_mfma<<<dim3(HC / 128, (N_NODES + 127) / 128), 256, 0, stream>>>(
        xb, W1t, h1p, as1, ad1, a_src1, a_dst1, N_NODES);
    agg1_fused<<<N_NODES / 4, 256, 0, stream>>>(rowstart, deg, csr_src, h1p, a_src1, a_dst1, b1, out1);

    /* layer 2 (h1p dead; aliased buffers safe, stream-ordered; att2 fused into gemm2) */
    gemm2_mfma<<<(N_NODES + 63) / 64, 256, 0, stream>>>(
        out1, W2t, h2, as2, ad2, a_src2, a_dst2, N_NODES);
    agg2_lsm<<<N_NODES / 4, 256, 0, stream>>>(rowstart, deg, csr_src, h2, a_src2, a_dst2, b2, (float*)d_out);
}